// Round 12
// baseline (60617.279 us; speedup 1.0000x reference)
//
#include <hip/hip_runtime.h>

typedef unsigned short u16;
typedef unsigned int   u32;
typedef __bf16 bf16x8 __attribute__((ext_vector_type(8)));
typedef float  f32x4  __attribute__((ext_vector_type(4)));
static_assert(sizeof(bf16x8) == 16, "bf16x8 size");

#define NL   219
#define NOUT 191

__device__ const int LAGS[6] = {1, 2, 3, 7, 14, 28};

// ---- workspace: packed weights (MFMA B-fragment order, hi/lo bf16) + scale.
// cell0: 128 ntile x 17 kb x 512  (kb16 = x-part: W_ih0 10 cols + 22 zero)
// cell1: 128 ntile x 32 kb x 512  (kb<16 = W_ih1 on h1; kb>=16 = W_hh1 on h2)
#define SZ_P0   2228224UL
#define SZ_P1   4194304UL
#define OFF_P0H 0UL
#define OFF_P0L (OFF_P0H + SZ_P0)
#define OFF_P1H (OFF_P0L + SZ_P0)
#define OFF_P1L (OFF_P1H + SZ_P1)
#define OFF_SC  (OFF_P1L + SZ_P1)
#define OFF_LS  (OFF_SC  + 2048UL)
#define WS_NEED (OFF_LS  + 2048UL)

__device__ __forceinline__ float sigm(float x){ return 1.f / (1.f + __expf(-x)); }
__device__ __forceinline__ float tanhx(float x){
  float ax = fabsf(x);
  float t  = __expf(-2.f * ax);
  float r  = (1.f - t) / (1.f + t);
  return copysignf(r, x);
}
__device__ __forceinline__ u16 f2bf(float x){
  u32 u = __float_as_uint(x);
  return (u16)((u + 0x7FFFu + ((u >> 16) & 1u)) >> 16);  // RNE
}
__device__ __forceinline__ float bf2f(u16 h){ return __uint_as_float(((u32)h) << 16); }

// ======================= prep: scale + weight packing (one sync via launch boundary)
__global__ __launch_bounds__(256) void prep(
    const float* __restrict__ X,    const float* __restrict__ Wih0,
    const float* __restrict__ Whh0, const float* __restrict__ Wih1,
    const float* __restrict__ Whh1, unsigned char* ws)
{
  __shared__ float redS[4];
  u16*  p0h = (u16*)(ws + OFF_P0H);
  u16*  p0l = (u16*)(ws + OFF_P0L);
  u16*  p1h = (u16*)(ws + OFF_P1H);
  u16*  p1l = (u16*)(ws + OFF_P1L);
  float* scp = (float*)(ws + OFF_SC);
  float* lsp = (float*)(ws + OFF_LS);
  const int tid = threadIdx.x, w = blockIdx.x;
  const int gtid = w * 256 + tid, G = 65536;
  // per-series scale (mean |x| over 168 context steps)
  {
    int rowb = w * 2 + (tid >> 7);
    int t0 = tid & 127;
    float a = fabsf(X[((size_t)rowb * NL + 28 + t0) * 3]);
    if (t0 < 40) a += fabsf(X[((size_t)rowb * NL + 156 + t0) * 3]);
    #pragma unroll
    for (int off = 1; off < 64; off <<= 1) a += __shfl_xor(a, off, 64);
    if ((tid & 63) == 0) redS[tid >> 6] = a;
    __syncthreads();
    if (tid == 0 || tid == 128){
      float s = redS[tid >> 6] + redS[(tid >> 6) + 1];
      float sc = fmaxf(s / 168.f, 0.001f);
      scp[rowb] = sc; lsp[rowb] = logf(sc);
    }
  }
  // pack cell0 B: [nt][17][512]; kb16 = x-part (Wih0, 10 real cols)
  for (int idx = gtid; idx < 1114112; idx += G){
    int e = idx & 7, ln = (idx >> 3) & 63;
    int rem = idx >> 9;
    int kb = rem % 17, nt = rem / 17;
    int n = (nt & 3) * 512 + (nt >> 2) * 16 + (ln & 15);
    int k = kb * 32 + (ln >> 4) * 8 + e;
    float wv;
    if (kb < 16) wv = Whh0[(size_t)n * 512 + k];
    else { int kk = k - 512; wv = (kk < 10) ? Wih0[(size_t)n * 10 + kk] : 0.f; }
    u16 hh = f2bf(wv);
    p0h[idx] = hh; p0l[idx] = f2bf(wv - bf2f(hh));
  }
  // pack cell1 B: [nt][32][512]
  for (int idx = gtid; idx < 2097152; idx += G){
    int e = idx & 7, ln = (idx >> 3) & 63, kb = (idx >> 9) & 31, nt = idx >> 14;
    int n = (nt & 3) * 512 + (nt >> 2) * 16 + (ln & 15);
    int k = kb * 32 + (ln >> 4) * 8 + e;
    float wv = (k < 512) ? Wih1[(size_t)n * 512 + k] : Whh1[(size_t)n * 512 + (k - 512)];
    u16 hh = f2bf(wv);
    p1h[idx] = hh; p1l[idx] = f2bf(wv - bf2f(hh));
  }
}

// ======================= run: 32 blocks x 16 rows, ZERO grid sync.
// Each block: full 2-layer LSTM recurrence for its 16 rows. h1/h2 in LDS
// (double-buffered, pad strides 552/520 u16 -> 2-way banks = free), c in regs,
// weights streamed from L3 (shared across the 4 lockstep blocks per XCD).
// K(cell0)=544: kb0-15 h1, kb16 = x (hi/lo split, same 3-term numerics).
__global__ __launch_bounds__(512, 1) void run(
    const float* __restrict__ X,  const float* __restrict__ b0,
    const float* __restrict__ b1, const float* __restrict__ Whead,
    const float* __restrict__ bhead, float* __restrict__ out,
    unsigned char* ws)
{
  __shared__ u16  h1s[35328];   // [2 buf][2 hi/lo][16][552]
  __shared__ u16  h2s[33280];   // [2 buf][2 hi/lo][16][520]
  __shared__ float WheadS[512];
  __shared__ float valpS[832];  // [16][52]
  __shared__ float scS[16], lsS[16], yS[16];

  const u16* p0h = (const u16*)(ws + OFF_P0H);
  const u16* p0l = (const u16*)(ws + OFF_P0L);
  const u16* p1h = (const u16*)(ws + OFF_P1H);
  const u16* p1l = (const u16*)(ws + OFF_P1L);
  const float* scp = (const float*)(ws + OFF_SC);
  const float* lsp = (const float*)(ws + OFF_LS);

  const int tid  = threadIdx.x;
  const int wave = tid >> 6;
  const int lane = tid & 63;
  const int r0   = blockIdx.x * 16;

  for (int i = tid; i < 35328; i += 512) h1s[i] = 0;
  for (int i = tid; i < 33280; i += 512) h2s[i] = 0;
  if (tid < 512) WheadS[tid] = Whead[tid];
  if (tid < 16){ scS[tid] = scp[r0 + tid]; lsS[tid] = lsp[r0 + tid]; yS[tid] = 0.f; }
  for (int i = tid; i < 448; i += 512){
    int r = i / 28, v = i % 28;
    valpS[r * 52 + v] = X[((size_t)(r0 + r) * NL + 168 + v) * 3] / scp[r0 + r];
  }
  float c1[16], c2[16];
  #pragma unroll
  for (int i = 0; i < 16; i++){ c1[i] = 0.f; c2[i] = 0.f; }
  const float bheadv = bhead[0];
  __syncthreads();

  int cur = 0;
  for (int t = 0; t < 191; t++){
    // ---- stage x(t) into h1s[cur] k-ext (cols 512..543), hi/lo split
    if (tid < 16){
      int r = tid; size_t xb = (size_t)(r0 + r) * NL;
      float sc = scS[r];
      float x0,x1,x2,x3,x4,x5,x6,x7,x8,x9;
      if (t < 168){
        x0 = X[(xb+28+t)*3] / sc; x1 = X[(xb+28+t)*3+1]; x2 = X[(xb+28+t)*3+2]; x3 = lsS[r];
        x4 = X[(xb+27+t)*3] / sc;  x5 = X[(xb+26+t)*3] / sc;  x6 = X[(xb+25+t)*3] / sc;
        x7 = X[(xb+21+t)*3] / sc;  x8 = X[(xb+14+t)*3] / sc;  x9 = X[(xb+t)*3] / sc;
      } else {
        int d = t - 168; float yp = yS[r];
        valpS[r*52 + 28 + d] = yp;
        x0 = yp; x1 = X[(xb+196+d)*3+1]; x2 = X[(xb+196+d)*3+2]; x3 = lsS[r];
        x4 = valpS[r*52 + 27 + d]; x5 = valpS[r*52 + 26 + d]; x6 = valpS[r*52 + 25 + d];
        x7 = valpS[r*52 + 21 + d]; x8 = valpS[r*52 + 14 + d]; x9 = valpS[r*52 + d];
      }
      u16* hx = h1s + (cur*2+0)*8832 + r*552 + 512;
      u16* lx = h1s + (cur*2+1)*8832 + r*552 + 512;
      #define PUTX(i,v) { u16 hh = f2bf(v); hx[i] = hh; lx[i] = f2bf((v) - bf2f(hh)); }
      PUTX(0,x0) PUTX(1,x1) PUTX(2,x2) PUTX(3,x3) PUTX(4,x4)
      PUTX(5,x5) PUTX(6,x6) PUTX(7,x7) PUTX(8,x8) PUTX(9,x9)
      #undef PUTX
      #pragma unroll
      for (int k = 10; k < 32; k++){ hx[k] = 0; lx[k] = 0; }
    }
    __syncthreads();
    const int nxt = cur ^ 1;

    // ---- cell0: K=544 (17 kb), gates -> c1/h1(t)
    {
      const u16* Ah = h1s + (cur*2+0)*8832;
      const u16* Al = h1s + (cur*2+1)*8832;
      const u32 aoff = (u32)(lane & 15) * 552 + (u32)(lane >> 4) * 8;
      const u32 l8 = (u32)lane * 8;
      u16* Hh = h1s + (nxt*2+0)*8832;
      u16* Hl = h1s + (nxt*2+1)*8832;
      #pragma unroll
      for (int cbi = 0; cbi < 4; cbi++){
        const int cb = wave * 4 + cbi;
        const int col = cb * 16 + (lane & 15);
        f32x4 a0, a1, a2, a3;
        { float b = b0[col];        a0 = (f32x4){b,b,b,b}; }
        { float b = b0[512 + col];  a1 = (f32x4){b,b,b,b}; }
        { float b = b0[1024 + col]; a2 = (f32x4){b,b,b,b}; }
        { float b = b0[1536 + col]; a3 = (f32x4){b,b,b,b}; }
        #pragma unroll 2
        for (int kb = 0; kb < 17; kb++){
          bf16x8 ah = *(const bf16x8*)(Ah + aoff + kb*32);
          bf16x8 al = *(const bf16x8*)(Al + aoff + kb*32);
          bf16x8 b0h = *(const bf16x8*)(p0h + (((u32)(cb*4+0)*17 + kb) << 9) + l8);
          bf16x8 b1h = *(const bf16x8*)(p0h + (((u32)(cb*4+1)*17 + kb) << 9) + l8);
          bf16x8 b2h = *(const bf16x8*)(p0h + (((u32)(cb*4+2)*17 + kb) << 9) + l8);
          bf16x8 b3h = *(const bf16x8*)(p0h + (((u32)(cb*4+3)*17 + kb) << 9) + l8);
          bf16x8 b0L = *(const bf16x8*)(p0l + (((u32)(cb*4+0)*17 + kb) << 9) + l8);
          bf16x8 b1L = *(const bf16x8*)(p0l + (((u32)(cb*4+1)*17 + kb) << 9) + l8);
          bf16x8 b2L = *(const bf16x8*)(p0l + (((u32)(cb*4+2)*17 + kb) << 9) + l8);
          bf16x8 b3L = *(const bf16x8*)(p0l + (((u32)(cb*4+3)*17 + kb) << 9) + l8);
          a0 = __builtin_amdgcn_mfma_f32_16x16x32_bf16(ah, b0h, a0, 0,0,0);
          a1 = __builtin_amdgcn_mfma_f32_16x16x32_bf16(ah, b1h, a1, 0,0,0);
          a2 = __builtin_amdgcn_mfma_f32_16x16x32_bf16(ah, b2h, a2, 0,0,0);
          a3 = __builtin_amdgcn_mfma_f32_16x16x32_bf16(ah, b3h, a3, 0,0,0);
          a0 = __builtin_amdgcn_mfma_f32_16x16x32_bf16(ah, b0L, a0, 0,0,0);
          a1 = __builtin_amdgcn_mfma_f32_16x16x32_bf16(ah, b1L, a1, 0,0,0);
          a2 = __builtin_amdgcn_mfma_f32_16x16x32_bf16(ah, b2L, a2, 0,0,0);
          a3 = __builtin_amdgcn_mfma_f32_16x16x32_bf16(ah, b3L, a3, 0,0,0);
          a0 = __builtin_amdgcn_mfma_f32_16x16x32_bf16(al, b0h, a0, 0,0,0);
          a1 = __builtin_amdgcn_mfma_f32_16x16x32_bf16(al, b1h, a1, 0,0,0);
          a2 = __builtin_amdgcn_mfma_f32_16x16x32_bf16(al, b2h, a2, 0,0,0);
          a3 = __builtin_amdgcn_mfma_f32_16x16x32_bf16(al, b3h, a3, 0,0,0);
        }
        #pragma unroll
        for (int r = 0; r < 4; r++){
          int row = (lane >> 4) * 4 + r;
          float gi = a0[r], gf = a1[r], gg = a2[r], go = a3[r];
          float co = c1[cbi*4 + r];
          float cn = sigm(gf) * co + sigm(gi) * tanhx(gg);
          float h  = sigm(go) * tanhx(cn);
          c1[cbi*4 + r] = cn;
          u16 hh = f2bf(h);
          Hh[row*552 + col] = hh;
          Hl[row*552 + col] = f2bf(h - bf2f(hh));
        }
      }
    }
    __syncthreads();

    // ---- cell1: K=1024 (kb0-15 = h1(t), kb16-31 = h2(t-1)) -> c2/h2(t)
    {
      const u16* A1h = h1s + (nxt*2+0)*8832;
      const u16* A1l = h1s + (nxt*2+1)*8832;
      const u16* A2h = h2s + (cur*2+0)*8320;
      const u16* A2l = h2s + (cur*2+1)*8320;
      const u32 ao1 = (u32)(lane & 15) * 552 + (u32)(lane >> 4) * 8;
      const u32 ao2 = (u32)(lane & 15) * 520 + (u32)(lane >> 4) * 8;
      const u32 l8 = (u32)lane * 8;
      u16* Hh = h2s + (nxt*2+0)*8320;
      u16* Hl = h2s + (nxt*2+1)*8320;
      #pragma unroll
      for (int cbi = 0; cbi < 4; cbi++){
        const int cb = wave * 4 + cbi;
        const int col = cb * 16 + (lane & 15);
        f32x4 a0, a1, a2, a3;
        { float b = b1[col];        a0 = (f32x4){b,b,b,b}; }
        { float b = b1[512 + col];  a1 = (f32x4){b,b,b,b}; }
        { float b = b1[1024 + col]; a2 = (f32x4){b,b,b,b}; }
        { float b = b1[1536 + col]; a3 = (f32x4){b,b,b,b}; }
        #pragma unroll 2
        for (int kb = 0; kb < 32; kb++){
          bf16x8 ah, al;
          if (kb < 16){
            ah = *(const bf16x8*)(A1h + ao1 + kb*32);
            al = *(const bf16x8*)(A1l + ao1 + kb*32);
          } else {
            ah = *(const bf16x8*)(A2h + ao2 + (kb-16)*32);
            al = *(const bf16x8*)(A2l + ao2 + (kb-16)*32);
          }
          bf16x8 b0h = *(const bf16x8*)(p1h + (((u32)(cb*4+0)*32 + kb) << 9) + l8);
          bf16x8 b1h = *(const bf16x8*)(p1h + (((u32)(cb*4+1)*32 + kb) << 9) + l8);
          bf16x8 b2h = *(const bf16x8*)(p1h + (((u32)(cb*4+2)*32 + kb) << 9) + l8);
          bf16x8 b3h = *(const bf16x8*)(p1h + (((u32)(cb*4+3)*32 + kb) << 9) + l8);
          bf16x8 b0L = *(const bf16x8*)(p1l + (((u32)(cb*4+0)*32 + kb) << 9) + l8);
          bf16x8 b1L = *(const bf16x8*)(p1l + (((u32)(cb*4+1)*32 + kb) << 9) + l8);
          bf16x8 b2L = *(const bf16x8*)(p1l + (((u32)(cb*4+2)*32 + kb) << 9) + l8);
          bf16x8 b3L = *(const bf16x8*)(p1l + (((u32)(cb*4+3)*32 + kb) << 9) + l8);
          a0 = __builtin_amdgcn_mfma_f32_16x16x32_bf16(ah, b0h, a0, 0,0,0);
          a1 = __builtin_amdgcn_mfma_f32_16x16x32_bf16(ah, b1h, a1, 0,0,0);
          a2 = __builtin_amdgcn_mfma_f32_16x16x32_bf16(ah, b2h, a2, 0,0,0);
          a3 = __builtin_amdgcn_mfma_f32_16x16x32_bf16(ah, b3h, a3, 0,0,0);
          a0 = __builtin_amdgcn_mfma_f32_16x16x32_bf16(ah, b0L, a0, 0,0,0);
          a1 = __builtin_amdgcn_mfma_f32_16x16x32_bf16(ah, b1L, a1, 0,0,0);
          a2 = __builtin_amdgcn_mfma_f32_16x16x32_bf16(ah, b2L, a2, 0,0,0);
          a3 = __builtin_amdgcn_mfma_f32_16x16x32_bf16(ah, b3L, a3, 0,0,0);
          a0 = __builtin_amdgcn_mfma_f32_16x16x32_bf16(al, b0h, a0, 0,0,0);
          a1 = __builtin_amdgcn_mfma_f32_16x16x32_bf16(al, b1h, a1, 0,0,0);
          a2 = __builtin_amdgcn_mfma_f32_16x16x32_bf16(al, b2h, a2, 0,0,0);
          a3 = __builtin_amdgcn_mfma_f32_16x16x32_bf16(al, b3h, a3, 0,0,0);
        }
        #pragma unroll
        for (int r = 0; r < 4; r++){
          int row = (lane >> 4) * 4 + r;
          float gi = a0[r], gf = a1[r], gg = a2[r], go = a3[r];
          float co = c2[cbi*4 + r];
          float cn = sigm(gf) * co + sigm(gi) * tanhx(gg);
          float h  = sigm(go) * tanhx(cn);
          c2[cbi*4 + r] = cn;
          u16 hh = f2bf(h);
          Hh[row*520 + col] = hh;
          Hl[row*520 + col] = f2bf(h - bf2f(hh));
        }
      }
    }
    __syncthreads();

    // ---- head: y = h2(t).Whead + b; out col t; yS feeds decoder
    {
      int row = tid >> 5, seg = tid & 31;
      const u16* hh = h2s + (nxt*2+0)*8320 + row*520 + seg*16;
      const u16* hl = h2s + (nxt*2+1)*8320 + row*520 + seg*16;
      const float* wv = WheadS + seg*16;
      float s = 0.f;
      #pragma unroll
      for (int c = 0; c < 16; c++) s += (bf2f(hh[c]) + bf2f(hl[c])) * wv[c];
      s += __shfl_xor(s, 1, 64);  s += __shfl_xor(s, 2, 64);
      s += __shfl_xor(s, 4, 64);  s += __shfl_xor(s, 8, 64);
      s += __shfl_xor(s, 16, 64);
      if (seg == 0){
        float y = s + bheadv;
        yS[row] = y;
        out[(size_t)(r0 + row) * NOUT + t] = y * scS[row];
      }
    }
    __syncthreads();
    cur = nxt;
  }
}

extern "C" void kernel_launch(void* const* d_in, const int* in_sizes, int n_in,
                              void* d_out, int out_size, void* d_ws, size_t ws_size,
                              hipStream_t stream) {
  (void)in_sizes; (void)n_in; (void)out_size;
  if (ws_size < WS_NEED) return;  // fail loudly (absmax) rather than corrupt
  const float* X    = (const float*)d_in[0];
  const float* Wih0 = (const float*)d_in[4];
  const float* Whh0 = (const float*)d_in[5];
  const float* b0   = (const float*)d_in[6];
  const float* Wih1 = (const float*)d_in[7];
  const float* Whh1 = (const float*)d_in[8];
  const float* b1   = (const float*)d_in[9];
  const float* Wh   = (const float*)d_in[10];
  const float* bh   = (const float*)d_in[11];
  float* out = (float*)d_out;
  unsigned char* ws = (unsigned char*)d_ws;

  prep<<<dim3(256), dim3(256), 0, stream>>>(X, Wih0, Whh0, Wih1, Whh1, ws);
  run<<<dim3(32), dim3(512), 0, stream>>>(X, b0, b1, Wh, bh, out, ws);
}